// Round 14
// baseline (161.039 us; speedup 1.0000x reference)
//
#include <hip/hip_runtime.h>
#include <hip/hip_bf16.h>
#include <stdint.h>

// Problem sizes (fixed by reference)
#define BT     8
#define T_SEQ  4096
#define K_F    512
#define N_H    1024
#define M_TOT  (BT * T_SEQ)   // 32768
#define NLAYER 4
#define LC     32             // chunk length for parallel scan
#define NC     (T_SEQ / LC)   // 128 chunks

typedef short  bf16x8 __attribute__((ext_vector_type(8)));
typedef float  f32x4  __attribute__((ext_vector_type(4)));
typedef ushort u16x8  __attribute__((ext_vector_type(8)));
typedef ushort u16x4  __attribute__((ext_vector_type(4)));

// f32 -> bf16 (round-to-nearest-even)
__device__ __forceinline__ ushort f2bf(float f) {
  uint32_t u = __builtin_bit_cast(uint32_t, f);
  u += 0x7fffu + ((u >> 16) & 1u);
  return (ushort)(u >> 16);
}
__device__ __forceinline__ float bf2f(ushort u) {
  uint32_t x = (uint32_t)u << 16;
  return __builtin_bit_cast(float, x);
}

// async global->LDS, 16B per lane (global_load_lds_dwordx4).
__device__ __forceinline__ void gload16(const void* g, void* l) {
  __builtin_amdgcn_global_load_lds(
      (const __attribute__((address_space(1))) uint32_t*)g,
      (__attribute__((address_space(3))) uint32_t*)l, 16, 0, 0);
}

// ---------------- prep: x f32->bf16 (8192 blocks) | W transpose (512 blocks) --
#define CVT_BLOCKS ((M_TOT * K_F) / (256 * 8))   // 8192

__global__ __launch_bounds__(256) void prep_kernel(const float* __restrict__ x,
                                                   ushort* __restrict__ xb,
                                                   const float* __restrict__ W,
                                                   ushort* __restrict__ Wt) {
  __shared__ float tile[32][33];
  const int bid = blockIdx.x;
  if (bid < CVT_BLOCKS) {
    const int i = bid * 256 + threadIdx.x;
    const f32x4* xv = (const f32x4*)x;   // ext_vector type: NT builtin accepts it
    // x is a read-once 64 MB stream: NT loads keep it from evicting xb (re-read 8x)
    f32x4 v0 = __builtin_nontemporal_load(xv + 2 * i + 0);
    f32x4 v1 = __builtin_nontemporal_load(xv + 2 * i + 1);
    u16x8 o;
    o[0] = f2bf(v0[0]); o[1] = f2bf(v0[1]); o[2] = f2bf(v0[2]); o[3] = f2bf(v0[3]);
    o[4] = f2bf(v1[0]); o[5] = f2bf(v1[1]); o[6] = f2bf(v1[2]); o[7] = f2bf(v1[3]);
    *((u16x8*)xb + i) = o;
  } else {
    const int idx = bid - CVT_BLOCKS;       // 0..511
    const int k0 = (idx & 15) * 32;         // 16 K-tiles
    const int n0 = (idx >> 4) * 32;         // 32 N-tiles
    const int lx = threadIdx.x & 31;
    const int ly = threadIdx.x >> 5;
#pragma unroll
    for (int j = 0; j < 32; j += 8)
      tile[ly + j][lx] = W[(size_t)(k0 + ly + j) * N_H + n0 + lx];
    __syncthreads();
#pragma unroll
    for (int j = 0; j < 32; j += 8)
      Wt[(size_t)(n0 + ly + j) * K_F + k0 + lx] = f2bf(tile[lx][ly + j]);
  }
}

// ---------------- GEMM + fused chunk-state (R7 trunk, unchanged) -----------
// Yb[M][N] = bf16(Xb[M][K] * Wt[N][K]^T + bias); m97 structure: 128x128 tile,
// BK=64, global_load_lds width=16, 2-barrier loop, 4 waves, ~4 blocks/CU.
// Epilogue: acc -> LDS bf16 tile (+bias) -> (a) coalesced u16x8 store to Yb,
// (b) fused SSM chunk-state (4 chunks x 128 h from LDS, bit-identical math).
#define BM 128
#define BN 128
#define BKK 64

__global__ __launch_bounds__(256) void gemm_kernel(
    const ushort* __restrict__ Xb, const ushort* __restrict__ Wt,
    const float* __restrict__ bias, ushort* __restrict__ Yb,
    const float* __restrict__ As, const float* __restrict__ Bs,
    const float* __restrict__ Cs, const float* __restrict__ Ds,
    float* __restrict__ E) {
  __shared__ ushort lds[BM * BKK * 2];   // lsA | lsB, 32 KiB; reused by epilogue
  ushort* lsA = lds;
  ushort* lsB = lds + BM * BKK;
  const int tid  = threadIdx.x;
  const int lane = tid & 63;
  const int wv   = tid >> 6;     // wave 0..3
  const int wr   = wv >> 1;      // wave row (0..1) -> 64 rows
  const int wc   = wv & 1;       // wave col (0..1) -> 64 cols
  const int m0   = blockIdx.x * BM;
  const int n0   = blockIdx.y * BN;

  const int srow = (lane >> 3);        // 0..7 within region
  const int scol = (lane & 7) * 8;     // k-elem offset
  const ushort* gA = Xb + (size_t)m0 * K_F + scol;
  const ushort* gB = Wt + (size_t)n0 * K_F + scol;

  f32x4 acc[4][4];
#pragma unroll
  for (int i = 0; i < 4; i++)
#pragma unroll
    for (int j = 0; j < 4; j++) acc[i][j] = (f32x4)0.0f;

  const int lr = lane & 15;
  const int kg = (lane >> 4) * 8;

  for (int kt = 0; kt < K_F; kt += BKK) {
#pragma unroll
    for (int i = 0; i < 4; i++) {
      const int reg = wv * 4 + i;          // region id 0..15
      const int r   = reg * 8 + srow;      // tile row
      gload16(gA + (size_t)r * K_F + kt, &lsA[reg * 512]);
      gload16(gB + (size_t)r * K_F + kt, &lsB[reg * 512]);
    }
    __syncthreads();

    bf16x8 af[4][2], bfr[4][2];
#pragma unroll
    for (int fm = 0; fm < 4; fm++)
#pragma unroll
      for (int kk = 0; kk < 2; kk++)
        af[fm][kk] = *(const bf16x8*)&lsA[(wr * 64 + fm * 16 + lr) * BKK + kk * 32 + kg];
#pragma unroll
    for (int fn = 0; fn < 4; fn++)
#pragma unroll
      for (int kk = 0; kk < 2; kk++)
        bfr[fn][kk] = *(const bf16x8*)&lsB[(wc * 64 + fn * 16 + lr) * BKK + kk * 32 + kg];

#pragma unroll
    for (int kk = 0; kk < 2; kk++)
#pragma unroll
      for (int fm = 0; fm < 4; fm++)
#pragma unroll
        for (int fn = 0; fn < 4; fn++)
          acc[fm][fn] = __builtin_amdgcn_mfma_f32_16x16x32_bf16(af[fm][kk], bfr[fn][kk],
                                                                acc[fm][fn], 0, 0, 0);
    __syncthreads();
  }

  // ---- epilogue, stage 1: acc -> LDS tile [128 t][128 h] bf16 (+bias) ----
#pragma unroll
  for (int fn = 0; fn < 4; fn++) {
    const int col = wc * 64 + fn * 16 + lr;
    const float bv = bias[n0 + col];
#pragma unroll
    for (int fm = 0; fm < 4; fm++) {
      const int row0 = wr * 64 + fm * 16 + (lane >> 4) * 4;
#pragma unroll
      for (int i = 0; i < 4; i++)
        lds[(row0 + i) * BN + col] = f2bf(acc[fm][fn][i] + bv);
    }
  }
  __syncthreads();

  // ---- epilogue, stage 2a: coalesced Yb store (256B rows) ----
  const int erow = tid >> 4;            // 0..15
  const int ecol = (tid & 15) * 8;      // elem offset, 16B per lane
#pragma unroll
  for (int p = 0; p < 8; p++) {
    const int row = p * 16 + erow;
    u16x8 v = *(const u16x8*)&lds[row * BN + ecol];
    *(u16x8*)&Yb[(size_t)(m0 + row) * N_H + n0 + ecol] = v;
  }

  // ---- epilogue, stage 2b: fused chunk-state over the LDS tile ----
  {
    const int bidx = m0 >> 12;           // m0 / T_SEQ
    const int c0   = (m0 & (T_SEQ - 1)) >> 5;  // first chunk in tile
    const int hl   = tid & 127;          // local h (same for both tasks)
    const int ck0  = tid >> 7;           // 0..1; tasks: ck0 and ck0+2
    const int h    = n0 + hl;

    float a[4], bb[4], cc[4], dd[4];
#pragma unroll
    for (int l = 0; l < 4; l++) {
      a[l]  = 1.f / (1.f + __expf(-As[l * N_H + h]));
      bb[l] = Bs[l * N_H + h];
      cc[l] = Cs[l * N_H + h];
      dd[l] = Ds[l * N_H + h];
    }

#pragma unroll
    for (int p = 0; p < 2; p++) {
      const int ck = ck0 + p * 2;
      float s[4] = {0.f, 0.f, 0.f, 0.f};
#pragma unroll 4
      for (int t = 0; t < LC; t++) {
        float xv = bf2f(lds[(ck * LC + t) * BN + hl]);
#pragma unroll
        for (int l = 0; l < 4; l++) {
          s[l] = fmaf(a[l], s[l], bb[l] * xv);
          xv = fmaf(cc[l], s[l], dd[l]);
        }
      }
      f32x4 e;
      e[0] = s[0]; e[1] = s[1]; e[2] = s[2]; e[3] = s[3];
      ((f32x4*)E)[(size_t)(bidx * NC + c0 + ck) * N_H + h] = e;
    }
  }
}

// ============ chunked parallel scan (passes B and C) ============
// Pass B: per-(b,h) serial combine over chunks with P=M^LC -> start states S.
__global__ __launch_bounds__(256) void chunk_scan_kernel(
    const float* __restrict__ A, const float* __restrict__ B,
    const float* __restrict__ C, const float* __restrict__ E,
    float* __restrict__ S) {
  const int idx = blockIdx.x * 256 + threadIdx.x;
  const int b = idx >> 10;
  const int h = idx & (N_H - 1);

  float a[4], bcoef[4], ccoef[4];
#pragma unroll
  for (int l = 0; l < 4; l++) {
    a[l] = 1.f / (1.f + __expf(-A[l * N_H + h]));
    bcoef[l] = B[l * N_H + h];
    ccoef[l] = C[l * N_H + h];
  }

  float m[4][4] = {};
  m[0][0] = a[0];
  m[1][0] = bcoef[1] * ccoef[0] * a[0];
  m[1][1] = a[1];
  m[2][0] = bcoef[2] * ccoef[1] * m[1][0];
  m[2][1] = bcoef[2] * ccoef[1] * a[1];
  m[2][2] = a[2];
  m[3][0] = bcoef[3] * ccoef[2] * m[2][0];
  m[3][1] = bcoef[3] * ccoef[2] * m[2][1];
  m[3][2] = bcoef[3] * ccoef[2] * a[2];
  m[3][3] = a[3];

  // P = M^LC, LC=32 -> 5 squarings
#pragma unroll
  for (int it = 0; it < 5; it++) {
    float t[4][4];
#pragma unroll
    for (int i = 0; i < 4; i++)
#pragma unroll
      for (int j = 0; j < 4; j++) {
        float acc = 0.f;
#pragma unroll
        for (int k = 0; k < 4; k++) acc = fmaf(m[i][k], m[k][j], acc);
        t[i][j] = acc;
      }
#pragma unroll
    for (int i = 0; i < 4; i++)
#pragma unroll
      for (int j = 0; j < 4; j++) m[i][j] = t[i][j];
  }

  float s[4] = {0.f, 0.f, 0.f, 0.f};
  const f32x4* Ep = (const f32x4*)E + (size_t)b * NC * N_H + h;
  f32x4* Sp = (f32x4*)S + (size_t)b * NC * N_H + h;
#pragma unroll 4
  for (int c = 0; c < NC; c++) {
    f32x4 sv;
    sv[0] = s[0]; sv[1] = s[1]; sv[2] = s[2]; sv[3] = s[3];
    Sp[(size_t)c * N_H] = sv;
    f32x4 e = __builtin_nontemporal_load(Ep + (size_t)c * N_H);  // E is last-use
    float ns[4];
#pragma unroll
    for (int i = 0; i < 4; i++) {
      float acc = e[i];
#pragma unroll
      for (int k = 0; k < 4; k++) acc = fmaf(m[i][k], s[k], acc);
      ns[i] = acc;
    }
#pragma unroll
    for (int i = 0; i < 4; i++) s[i] = ns[i];
  }
}

// Pass C: recurrence from exact start state; reads bf16 Y (last-use, NT),
// writes f32 out (write-once stream, NT stores — R12's measured -11 us win).
__global__ __launch_bounds__(256) void chunk_apply_kernel(
    const ushort* __restrict__ Yb, float* __restrict__ out,
    const float* __restrict__ A, const float* __restrict__ B,
    const float* __restrict__ C, const float* __restrict__ D,
    const float* __restrict__ S) {
  const int b  = blockIdx.x / NC;
  const int c  = blockIdx.x % NC;
  const int h4 = threadIdx.x << 2;

  float a[4][4], bb[4][4], cc[4][4], dd[4][4];
#pragma unroll
  for (int l = 0; l < 4; l++) {
    f32x4 av = *(const f32x4*)(A + l * N_H + h4);
    f32x4 bv = *(const f32x4*)(B + l * N_H + h4);
    f32x4 cv = *(const f32x4*)(C + l * N_H + h4);
    f32x4 dv = *(const f32x4*)(D + l * N_H + h4);
#pragma unroll
    for (int ch = 0; ch < 4; ch++) {
      a[l][ch]  = 1.f / (1.f + __expf(-av[ch]));
      bb[l][ch] = bv[ch]; cc[l][ch] = cv[ch]; dd[l][ch] = dv[ch];
    }
  }

  float s[4][4];
  const f32x4* sp = (const f32x4*)S + (size_t)(b * NC + c) * N_H + h4;
#pragma unroll
  for (int ch = 0; ch < 4; ch++) {
    f32x4 sv = __builtin_nontemporal_load(sp + ch);   // S is last-use
    s[0][ch] = sv[0]; s[1][ch] = sv[1]; s[2][ch] = sv[2]; s[3][ch] = sv[3];
  }

  const ushort* ybase = Yb + ((size_t)b * T_SEQ + (size_t)c * LC) * N_H + h4;
  f32x4* op = (f32x4*)(out + ((size_t)b * T_SEQ + (size_t)c * LC) * N_H) + (h4 >> 2);
#pragma unroll 4
  for (int t = 0; t < LC; t++) {
    u16x4 xv = __builtin_nontemporal_load(
        (const u16x4*)(ybase + (size_t)t * N_H));     // Yb is last-use
    f32x4 ov;
#pragma unroll
    for (int ch = 0; ch < 4; ch++) {
      float x = bf2f(xv[ch]);
#pragma unroll
      for (int l = 0; l < 4; l++) {
        s[l][ch] = fmaf(a[l][ch], s[l][ch], bb[l][ch] * x);
        x = fmaf(cc[l][ch], s[l][ch], dd[l][ch]);
      }
      ov[ch] = x;
    }
    __builtin_nontemporal_store(ov, op + (size_t)t * (N_H / 4));
  }
}

extern "C" void kernel_launch(void* const* d_in, const int* in_sizes, int n_in,
                              void* d_out, int out_size, void* d_ws, size_t ws_size,
                              hipStream_t stream) {
  const float* x    = (const float*)d_in[0];
  const float* W    = (const float*)d_in[1];
  const float* b_in = (const float*)d_in[2];
  const float* A    = (const float*)d_in[3];
  const float* B    = (const float*)d_in[4];
  const float* C    = (const float*)d_in[5];
  const float* bias = (const float*)d_in[6];
  float* out = (float*)d_out;

  // ws layout (512 MiB available):
  //   xb  [0,   32 MiB)  bf16 x
  //   Wt  [32,  33 MiB)  bf16 W^T
  //   Yb  [40, 104 MiB)  bf16 intermediate Y
  //   E   [112,128 MiB)  f32 chunk end states
  //   S   [128,144 MiB)  f32 chunk start states
  char* wsb = (char*)d_ws;
  ushort* xb = (ushort*)wsb;
  ushort* Wt = (ushort*)(wsb + (size_t)33 * 1024 * 1024 - (size_t)N_H * K_F * 2);
  ushort* Yb = (ushort*)(wsb + (size_t)40 * 1024 * 1024);
  float*  E  = (float*)(wsb + (size_t)112 * 1024 * 1024);
  float*  S  = E + (size_t)BT * NC * N_H * 4;

  prep_kernel<<<CVT_BLOCKS + 512, 256, 0, stream>>>(x, xb, W, Wt);
  gemm_kernel<<<dim3(M_TOT / BM, N_H / BN), 256, 0, stream>>>(xb, Wt, b_in, Yb,
                                                              A, B, C, bias, E);
  chunk_scan_kernel<<<(BT * N_H) / 256, 256, 0, stream>>>(A, B, C, E, S);
  chunk_apply_kernel<<<BT * NC, 256, 0, stream>>>(Yb, out, A, B, C, bias, S);
}

// Round 15
// 136.000 us; speedup vs baseline: 1.1841x; 1.1841x over previous
//
#include <hip/hip_runtime.h>
#include <hip/hip_bf16.h>
#include <stdint.h>

// Problem sizes (fixed by reference)
#define BT     8
#define T_SEQ  4096
#define K_F    512
#define N_H    1024
#define M_TOT  (BT * T_SEQ)   // 32768
#define NLAYER 4
#define LC     32             // chunk length for parallel scan
#define NC     (T_SEQ / LC)   // 128 chunks

typedef short  bf16x8 __attribute__((ext_vector_type(8)));
typedef float  f32x4  __attribute__((ext_vector_type(4)));
typedef ushort u16x8  __attribute__((ext_vector_type(8)));
typedef ushort u16x4  __attribute__((ext_vector_type(4)));

// f32 -> bf16 (round-to-nearest-even)
__device__ __forceinline__ ushort f2bf(float f) {
  uint32_t u = __builtin_bit_cast(uint32_t, f);
  u += 0x7fffu + ((u >> 16) & 1u);
  return (ushort)(u >> 16);
}
__device__ __forceinline__ float bf2f(ushort u) {
  uint32_t x = (uint32_t)u << 16;
  return __builtin_bit_cast(float, x);
}

// async global->LDS, 16B per lane (global_load_lds_dwordx4).
__device__ __forceinline__ void gload16(const void* g, void* l) {
  __builtin_amdgcn_global_load_lds(
      (const __attribute__((address_space(1))) uint32_t*)g,
      (__attribute__((address_space(3))) uint32_t*)l, 16, 0, 0);
}

// ---------------- prep: x f32->bf16 (8192 blocks) | W transpose (512 blocks) --
#define CVT_BLOCKS ((M_TOT * K_F) / (256 * 8))   // 8192

__global__ __launch_bounds__(256) void prep_kernel(const float* __restrict__ x,
                                                   ushort* __restrict__ xb,
                                                   const float* __restrict__ W,
                                                   ushort* __restrict__ Wt) {
  __shared__ float tile[32][33];
  const int bid = blockIdx.x;
  if (bid < CVT_BLOCKS) {
    const int i = bid * 256 + threadIdx.x;
    const float4* xv = (const float4*)x;    // plain loads (NT loads measured -15us, R14)
    float4 v0 = xv[2 * i + 0];
    float4 v1 = xv[2 * i + 1];
    u16x8 o;
    o[0] = f2bf(v0.x); o[1] = f2bf(v0.y); o[2] = f2bf(v0.z); o[3] = f2bf(v0.w);
    o[4] = f2bf(v1.x); o[5] = f2bf(v1.y); o[6] = f2bf(v1.z); o[7] = f2bf(v1.w);
    *((u16x8*)xb + i) = o;
  } else {
    const int idx = bid - CVT_BLOCKS;       // 0..511
    const int k0 = (idx & 15) * 32;         // 16 K-tiles
    const int n0 = (idx >> 4) * 32;         // 32 N-tiles
    const int lx = threadIdx.x & 31;
    const int ly = threadIdx.x >> 5;
#pragma unroll
    for (int j = 0; j < 32; j += 8)
      tile[ly + j][lx] = W[(size_t)(k0 + ly + j) * N_H + n0 + lx];
    __syncthreads();
#pragma unroll
    for (int j = 0; j < 32; j += 8)
      Wt[(size_t)(n0 + ly + j) * K_F + k0 + lx] = f2bf(tile[lx][ly + j]);
  }
}

// ---------------- GEMM + fused chunk-state -------------------------------
// R12 trunk with the K-loop pipelined per the T3 "minimum 2-phase" recipe:
//   BK=32, double-buffered LDS (2 x 16 KiB = 32 KiB total, occupancy kept),
//   per iter: { stage(kt+1 -> buf^1) ; ds_read(buf) + 16 MFMA ; __syncthreads }
// One sync per iter (16 total = same count as R12's 8x2) but the staged loads
// fly UNDER the compute phase instead of being drained before it.
// Race-free (R9 argument): reads of buf^1 were drained at the previous sync,
// and the staged tile lands at this iter's sync (vmcnt(0) before s_barrier).
// BK=32 also halves the ds_read row stride (64B) -> 8-way bank conflict
// instead of 16-way. Epilogue + fused chunk-state byte-identical to R12.
#define BM 128
#define BN 128
#define BKK 32
#define NKT (K_F / BKK)   // 16 K-iterations

__global__ __launch_bounds__(256) void gemm_kernel(
    const ushort* __restrict__ Xb, const ushort* __restrict__ Wt,
    const float* __restrict__ bias, ushort* __restrict__ Yb,
    const float* __restrict__ As, const float* __restrict__ Bs,
    const float* __restrict__ Cs, const float* __restrict__ Ds,
    float* __restrict__ E) {
  // 2 buffers x (A 4096 + B 4096 elems) = 16384 ushort = 32 KiB.
  // Epilogue reuses the whole array as a [128][128] bf16 tile.
  __shared__ ushort lds[16384];
  const int tid  = threadIdx.x;
  const int lane = tid & 63;
  const int wv   = tid >> 6;     // wave 0..3
  const int wr   = wv >> 1;      // wave row (0..1) -> 64 rows
  const int wc   = wv & 1;       // wave col (0..1) -> 64 cols
  const int m0   = blockIdx.x * BM;
  const int n0   = blockIdx.y * BN;

  // staging: per buffer, A = 8 regions x 1KB, B = 8 regions x 1KB.
  // region r covers rows r*16 + (lane>>2), k-elems (lane&3)*8  (row-major [128][32])
  const int arow = lane >> 2;          // 0..15
  const int acol = (lane & 3) * 8;     // k-elem offset
  const ushort* gA = Xb + (size_t)m0 * K_F + acol;
  const ushort* gB = Wt + (size_t)n0 * K_F + acol;

  f32x4 acc[4][4];
#pragma unroll
  for (int i = 0; i < 4; i++)
#pragma unroll
    for (int j = 0; j < 4; j++) acc[i][j] = (f32x4)0.0f;

  const int lr = lane & 15;
  const int kg = (lane >> 4) * 8;      // k-group within BK=32

#define STAGE(kt, buf)                                                        \
  do {                                                                        \
    ushort* _a = &lds[(buf) * 8192];                                          \
    ushort* _b = &lds[(buf) * 8192 + 4096];                                   \
    _Pragma("unroll")                                                         \
    for (int _i = 0; _i < 2; _i++) {                                          \
      const int _r = wv * 2 + _i;      /* region 0..7 */                      \
      gload16(gA + (size_t)(_r * 16 + arow) * K_F + (kt) * BKK, &_a[_r * 512]); \
      gload16(gB + (size_t)(_r * 16 + arow) * K_F + (kt) * BKK, &_b[_r * 512]); \
    }                                                                         \
  } while (0)

  STAGE(0, 0);
  __syncthreads();   // tile 0 resident

  for (int kt = 0; kt < NKT; kt++) {
    const int buf = kt & 1;
    if (kt + 1 < NKT) STAGE(kt + 1, buf ^ 1);   // in flight under compute

    const ushort* la = &lds[buf * 8192];
    const ushort* lb = &lds[buf * 8192 + 4096];
    bf16x8 af[4], bfr[4];
#pragma unroll
    for (int fm = 0; fm < 4; fm++)
      af[fm] = *(const bf16x8*)&la[(wr * 64 + fm * 16 + lr) * BKK + kg];
#pragma unroll
    for (int fn = 0; fn < 4; fn++)
      bfr[fn] = *(const bf16x8*)&lb[(wc * 64 + fn * 16 + lr) * BKK + kg];

#pragma unroll
    for (int fm = 0; fm < 4; fm++)
#pragma unroll
      for (int fn = 0; fn < 4; fn++)
        acc[fm][fn] = __builtin_amdgcn_mfma_f32_16x16x32_bf16(af[fm], bfr[fn],
                                                              acc[fm][fn], 0, 0, 0);
    __syncthreads();   // drains vmcnt (staged tile landed) + lgkm (reads done)
  }
#undef STAGE

  // ---- epilogue, stage 1: acc -> LDS tile [128 t][128 h] bf16 (+bias) ----
#pragma unroll
  for (int fn = 0; fn < 4; fn++) {
    const int col = wc * 64 + fn * 16 + lr;
    const float bv = bias[n0 + col];
#pragma unroll
    for (int fm = 0; fm < 4; fm++) {
      const int row0 = wr * 64 + fm * 16 + (lane >> 4) * 4;
#pragma unroll
      for (int i = 0; i < 4; i++)
        lds[(row0 + i) * BN + col] = f2bf(acc[fm][fn][i] + bv);
    }
  }
  __syncthreads();

  // ---- epilogue, stage 2a: coalesced Yb store (256B rows) ----
  const int erow = tid >> 4;            // 0..15
  const int ecol = (tid & 15) * 8;      // elem offset, 16B per lane
#pragma unroll
  for (int p = 0; p < 8; p++) {
    const int row = p * 16 + erow;
    u16x8 v = *(const u16x8*)&lds[row * BN + ecol];
    *(u16x8*)&Yb[(size_t)(m0 + row) * N_H + n0 + ecol] = v;
  }

  // ---- epilogue, stage 2b: fused chunk-state over the LDS tile ----
  {
    const int bidx = m0 >> 12;           // m0 / T_SEQ
    const int c0   = (m0 & (T_SEQ - 1)) >> 5;  // first chunk in tile
    const int hl   = tid & 127;          // local h (same for both tasks)
    const int ck0  = tid >> 7;           // 0..1; tasks: ck0 and ck0+2
    const int h    = n0 + hl;

    float a[4], bb[4], cc[4], dd[4];
#pragma unroll
    for (int l = 0; l < 4; l++) {
      a[l]  = 1.f / (1.f + __expf(-As[l * N_H + h]));
      bb[l] = Bs[l * N_H + h];
      cc[l] = Cs[l * N_H + h];
      dd[l] = Ds[l * N_H + h];
    }

#pragma unroll
    for (int p = 0; p < 2; p++) {
      const int ck = ck0 + p * 2;
      float s[4] = {0.f, 0.f, 0.f, 0.f};
#pragma unroll 4
      for (int t = 0; t < LC; t++) {
        float xv = bf2f(lds[(ck * LC + t) * BN + hl]);
#pragma unroll
        for (int l = 0; l < 4; l++) {
          s[l] = fmaf(a[l], s[l], bb[l] * xv);
          xv = fmaf(cc[l], s[l], dd[l]);
        }
      }
      f32x4 e;
      e[0] = s[0]; e[1] = s[1]; e[2] = s[2]; e[3] = s[3];
      ((f32x4*)E)[(size_t)(bidx * NC + c0 + ck) * N_H + h] = e;
    }
  }
}

// ============ chunked parallel scan (passes B and C) ============
// Pass B: per-(b,h) serial combine over chunks with P=M^LC -> start states S.
__global__ __launch_bounds__(256) void chunk_scan_kernel(
    const float* __restrict__ A, const float* __restrict__ B,
    const float* __restrict__ C, const float* __restrict__ E,
    float* __restrict__ S) {
  const int idx = blockIdx.x * 256 + threadIdx.x;
  const int b = idx >> 10;
  const int h = idx & (N_H - 1);

  float a[4], bcoef[4], ccoef[4];
#pragma unroll
  for (int l = 0; l < 4; l++) {
    a[l] = 1.f / (1.f + __expf(-A[l * N_H + h]));
    bcoef[l] = B[l * N_H + h];
    ccoef[l] = C[l * N_H + h];
  }

  float m[4][4] = {};
  m[0][0] = a[0];
  m[1][0] = bcoef[1] * ccoef[0] * a[0];
  m[1][1] = a[1];
  m[2][0] = bcoef[2] * ccoef[1] * m[1][0];
  m[2][1] = bcoef[2] * ccoef[1] * a[1];
  m[2][2] = a[2];
  m[3][0] = bcoef[3] * ccoef[2] * m[2][0];
  m[3][1] = bcoef[3] * ccoef[2] * m[2][1];
  m[3][2] = bcoef[3] * ccoef[2] * a[2];
  m[3][3] = a[3];

  // P = M^LC, LC=32 -> 5 squarings
#pragma unroll
  for (int it = 0; it < 5; it++) {
    float t[4][4];
#pragma unroll
    for (int i = 0; i < 4; i++)
#pragma unroll
      for (int j = 0; j < 4; j++) {
        float acc = 0.f;
#pragma unroll
        for (int k = 0; k < 4; k++) acc = fmaf(m[i][k], m[k][j], acc);
        t[i][j] = acc;
      }
#pragma unroll
    for (int i = 0; i < 4; i++)
#pragma unroll
      for (int j = 0; j < 4; j++) m[i][j] = t[i][j];
  }

  float s[4] = {0.f, 0.f, 0.f, 0.f};
  const f32x4* Ep = (const f32x4*)E + (size_t)b * NC * N_H + h;
  f32x4* Sp = (f32x4*)S + (size_t)b * NC * N_H + h;
#pragma unroll 4
  for (int c = 0; c < NC; c++) {
    f32x4 sv;
    sv[0] = s[0]; sv[1] = s[1]; sv[2] = s[2]; sv[3] = s[3];
    Sp[(size_t)c * N_H] = sv;
    f32x4 e = Ep[(size_t)c * N_H];
    float ns[4];
#pragma unroll
    for (int i = 0; i < 4; i++) {
      float acc = e[i];
#pragma unroll
      for (int k = 0; k < 4; k++) acc = fmaf(m[i][k], s[k], acc);
      ns[i] = acc;
    }
#pragma unroll
    for (int i = 0; i < 4; i++) s[i] = ns[i];
  }
}

// Pass C: recurrence from exact start state; reads bf16 Y, writes f32 out.
// `out` is a 134 MB write-once stream -> NT stores (R12's measured -11us win).
// Reads stay cached (NT loads measured -15us, R14).
__global__ __launch_bounds__(256) void chunk_apply_kernel(
    const ushort* __restrict__ Yb, float* __restrict__ out,
    const float* __restrict__ A, const float* __restrict__ B,
    const float* __restrict__ C, const float* __restrict__ D,
    const float* __restrict__ S) {
  const int b  = blockIdx.x / NC;
  const int c  = blockIdx.x % NC;
  const int h4 = threadIdx.x << 2;

  float a[4][4], bb[4][4], cc[4][4], dd[4][4];
#pragma unroll
  for (int l = 0; l < 4; l++) {
    f32x4 av = *(const f32x4*)(A + l * N_H + h4);
    f32x4 bv = *(const f32x4*)(B + l * N_H + h4);
    f32x4 cv = *(const f32x4*)(C + l * N_H + h4);
    f32x4 dv = *(const f32x4*)(D + l * N_H + h4);
#pragma unroll
    for (int ch = 0; ch < 4; ch++) {
      a[l][ch]  = 1.f / (1.f + __expf(-av[ch]));
      bb[l][ch] = bv[ch]; cc[l][ch] = cv[ch]; dd[l][ch] = dv[ch];
    }
  }

  float s[4][4];
  const f32x4* sp = (const f32x4*)S + (size_t)(b * NC + c) * N_H + h4;
#pragma unroll
  for (int ch = 0; ch < 4; ch++) {
    f32x4 sv = sp[ch];
    s[0][ch] = sv[0]; s[1][ch] = sv[1]; s[2][ch] = sv[2]; s[3][ch] = sv[3];
  }

  const ushort* ybase = Yb + ((size_t)b * T_SEQ + (size_t)c * LC) * N_H + h4;
  f32x4* op = (f32x4*)(out + ((size_t)b * T_SEQ + (size_t)c * LC) * N_H) + (h4 >> 2);
#pragma unroll 4
  for (int t = 0; t < LC; t++) {
    u16x4 xv = *(const u16x4*)(ybase + (size_t)t * N_H);
    f32x4 ov;
#pragma unroll
    for (int ch = 0; ch < 4; ch++) {
      float x = bf2f(xv[ch]);
#pragma unroll
      for (int l = 0; l < 4; l++) {
        s[l][ch] = fmaf(a[l][ch], s[l][ch], bb[l][ch] * x);
        x = fmaf(cc[l][ch], s[l][ch], dd[l][ch]);
      }
      ov[ch] = x;
    }
    __builtin_nontemporal_store(ov, op + (size_t)t * (N_H / 4));
  }
}

extern "C" void kernel_launch(void* const* d_in, const int* in_sizes, int n_in,
                              void* d_out, int out_size, void* d_ws, size_t ws_size,
                              hipStream_t stream) {
  const float* x    = (const float*)d_in[0];
  const float* W    = (const float*)d_in[1];
  const float* b_in = (const float*)d_in[2];
  const float* A    = (const float*)d_in[3];
  const float* B    = (const float*)d_in[4];
  const float* C    = (const float*)d_in[5];
  const float* bias = (const float*)d_in[6];
  float* out = (float*)d_out;

  // ws layout (512 MiB available):
  //   xb  [0,   32 MiB)  bf16 x
  //   Wt  [32,  33 MiB)  bf16 W^T
  //   Yb  [40, 104 MiB)  bf16 intermediate Y
  //   E   [112,128 MiB)  f32 chunk end states
  //   S   [128,144 MiB)  f32 chunk start states
  char* wsb = (char*)d_ws;
  ushort* xb = (ushort*)wsb;
  ushort* Wt = (ushort*)(wsb + (size_t)33 * 1024 * 1024 - (size_t)N_H * K_F * 2);
  ushort* Yb = (ushort*)(wsb + (size_t)40 * 1024 * 1024);
  float*  E  = (float*)(wsb + (size_t)112 * 1024 * 1024);
  float*  S  = E + (size_t)BT * NC * N_H * 4;

  prep_kernel<<<CVT_BLOCKS + 512, 256, 0, stream>>>(x, xb, W, Wt);
  gemm_kernel<<<dim3(M_TOT / BM, N_H / BN), 256, 0, stream>>>(xb, Wt, b_in, Yb,
                                                              A, B, C, bias, E);
  chunk_scan_kernel<<<(BT * N_H) / 256, 256, 0, stream>>>(A, B, C, E, S);
  chunk_apply_kernel<<<BT * NC, 256, 0, stream>>>(Yb, out, A, B, C, bias, S);
}

// Round 16
// 135.380 us; speedup vs baseline: 1.1895x; 1.0046x over previous
//
#include <hip/hip_runtime.h>
#include <hip/hip_bf16.h>
#include <stdint.h>

// Problem sizes (fixed by reference)
#define BT     8
#define T_SEQ  4096
#define K_F    512
#define N_H    1024
#define M_TOT  (BT * T_SEQ)   // 32768
#define NLAYER 4
#define LC     32             // chunk length for parallel scan
#define NC     (T_SEQ / LC)   // 128 chunks

typedef short  bf16x8 __attribute__((ext_vector_type(8)));
typedef float  f32x4  __attribute__((ext_vector_type(4)));
typedef ushort u16x8  __attribute__((ext_vector_type(8)));
typedef ushort u16x4  __attribute__((ext_vector_type(4)));

// f32 -> bf16 (round-to-nearest-even)
__device__ __forceinline__ ushort f2bf(float f) {
  uint32_t u = __builtin_bit_cast(uint32_t, f);
  u += 0x7fffu + ((u >> 16) & 1u);
  return (ushort)(u >> 16);
}
__device__ __forceinline__ float bf2f(ushort u) {
  uint32_t x = (uint32_t)u << 16;
  return __builtin_bit_cast(float, x);
}

// async global->LDS, 16B per lane (global_load_lds_dwordx4).
__device__ __forceinline__ void gload16(const void* g, void* l) {
  __builtin_amdgcn_global_load_lds(
      (const __attribute__((address_space(1))) uint32_t*)g,
      (__attribute__((address_space(3))) uint32_t*)l, 16, 0, 0);
}

// ---------------- prep: x f32->bf16 (8192 blocks) | W transpose (512 blocks) --
#define CVT_BLOCKS ((M_TOT * K_F) / (256 * 8))   // 8192

__global__ __launch_bounds__(256) void prep_kernel(const float* __restrict__ x,
                                                   ushort* __restrict__ xb,
                                                   const float* __restrict__ W,
                                                   ushort* __restrict__ Wt) {
  __shared__ float tile[32][33];
  const int bid = blockIdx.x;
  if (bid < CVT_BLOCKS) {
    const int i = bid * 256 + threadIdx.x;
    const float4* xv = (const float4*)x;    // plain loads (NT loads measured -15us, R14)
    float4 v0 = xv[2 * i + 0];
    float4 v1 = xv[2 * i + 1];
    u16x8 o;
    o[0] = f2bf(v0.x); o[1] = f2bf(v0.y); o[2] = f2bf(v0.z); o[3] = f2bf(v0.w);
    o[4] = f2bf(v1.x); o[5] = f2bf(v1.y); o[6] = f2bf(v1.z); o[7] = f2bf(v1.w);
    *((u16x8*)xb + i) = o;
  } else {
    const int idx = bid - CVT_BLOCKS;       // 0..511
    const int k0 = (idx & 15) * 32;         // 16 K-tiles
    const int n0 = (idx >> 4) * 32;         // 32 N-tiles
    const int lx = threadIdx.x & 31;
    const int ly = threadIdx.x >> 5;
#pragma unroll
    for (int j = 0; j < 32; j += 8)
      tile[ly + j][lx] = W[(size_t)(k0 + ly + j) * N_H + n0 + lx];
    __syncthreads();
#pragma unroll
    for (int j = 0; j < 32; j += 8)
      Wt[(size_t)(n0 + ly + j) * K_F + k0 + lx] = f2bf(tile[lx][ly + j]);
  }
}

// ---------------- GEMM + fused chunk-state -------------------------------
// R15 trunk (BK=32 double-buffered 2-phase pipeline, 1 sync/iter) plus a
// bank-conflict fix for the ds_read side (R16):
//   The [128][32] row-major tile (64B rows = 16 banks) gives fragment reads
//   an 8-way bank conflict. Fix per rule #21 (both-sides-or-neither with
//   global_load_lds): LDS dest stays linear; the GLOBAL source is pre-swizzled
//   so physical 16B-slot p of row r holds logical slot p ^ ((r>>1)&3); reads
//   apply the same involution. 16 consecutive rows then spread over 8
//   bank-quads -> 2-way conflict (free, m136). Coalescing unaffected (the
//   permutation stays within each 64B row). Math bit-identical.
#define BM 128
#define BN 128
#define BKK 32
#define NKT (K_F / BKK)   // 16 K-iterations

__global__ __launch_bounds__(256) void gemm_kernel(
    const ushort* __restrict__ Xb, const ushort* __restrict__ Wt,
    const float* __restrict__ bias, ushort* __restrict__ Yb,
    const float* __restrict__ As, const float* __restrict__ Bs,
    const float* __restrict__ Cs, const float* __restrict__ Ds,
    float* __restrict__ E) {
  // 2 buffers x (A 4096 + B 4096 elems) = 16384 ushort = 32 KiB.
  // Epilogue reuses the whole array as a [128][128] bf16 tile.
  __shared__ ushort lds[16384];
  const int tid  = threadIdx.x;
  const int lane = tid & 63;
  const int wv   = tid >> 6;     // wave 0..3
  const int wr   = wv >> 1;      // wave row (0..1) -> 64 rows
  const int wc   = wv & 1;       // wave col (0..1) -> 64 cols
  const int m0   = blockIdx.x * BM;
  const int n0   = blockIdx.y * BN;

  // staging: per buffer, A = 8 regions x 1KB, B = 8 regions x 1KB.
  // region r covers rows r*16 + (lane>>2); lane's LDS slot is (lane&3) (16B).
  // Source pre-swizzle: load logical slot (lane&3) ^ ((arow>>1)&3), where
  // arow = lane>>2, so (arow>>1)&3 = (lane>>3)&3.
  const int arow = lane >> 2;          // 0..15
  const int acol = (((lane & 3) ^ ((lane >> 3) & 3)) * 8);   // swizzled k-elem
  const ushort* gA = Xb + (size_t)m0 * K_F + acol;
  const ushort* gB = Wt + (size_t)n0 * K_F + acol;

  f32x4 acc[4][4];
#pragma unroll
  for (int i = 0; i < 4; i++)
#pragma unroll
    for (int j = 0; j < 4; j++) acc[i][j] = (f32x4)0.0f;

  const int lr = lane & 15;
  // read-side swizzle: logical slot = lane>>4; physical = slot ^ ((row>>1)&3),
  // and row = (wave base) + lr with base ≡ 0 mod 16, so (row>>1)&3 = (lr>>1)&3.
  const int kswz = ((lane >> 4) ^ ((lr >> 1) & 3)) * 8;   // elem offset in row

#define STAGE(kt, buf)                                                        \
  do {                                                                        \
    ushort* _a = &lds[(buf) * 8192];                                          \
    ushort* _b = &lds[(buf) * 8192 + 4096];                                   \
    _Pragma("unroll")                                                         \
    for (int _i = 0; _i < 2; _i++) {                                          \
      const int _r = wv * 2 + _i;      /* region 0..7 */                      \
      gload16(gA + (size_t)(_r * 16 + arow) * K_F + (kt) * BKK, &_a[_r * 512]); \
      gload16(gB + (size_t)(_r * 16 + arow) * K_F + (kt) * BKK, &_b[_r * 512]); \
    }                                                                         \
  } while (0)

  STAGE(0, 0);
  __syncthreads();   // tile 0 resident

  for (int kt = 0; kt < NKT; kt++) {
    const int buf = kt & 1;
    if (kt + 1 < NKT) STAGE(kt + 1, buf ^ 1);   // in flight under compute

    const ushort* la = &lds[buf * 8192];
    const ushort* lb = &lds[buf * 8192 + 4096];
    bf16x8 af[4], bfr[4];
#pragma unroll
    for (int fm = 0; fm < 4; fm++)
      af[fm] = *(const bf16x8*)&la[(wr * 64 + fm * 16 + lr) * BKK + kswz];
#pragma unroll
    for (int fn = 0; fn < 4; fn++)
      bfr[fn] = *(const bf16x8*)&lb[(wc * 64 + fn * 16 + lr) * BKK + kswz];

#pragma unroll
    for (int fm = 0; fm < 4; fm++)
#pragma unroll
      for (int fn = 0; fn < 4; fn++)
        acc[fm][fn] = __builtin_amdgcn_mfma_f32_16x16x32_bf16(af[fm], bfr[fn],
                                                              acc[fm][fn], 0, 0, 0);
    __syncthreads();   // drains vmcnt (staged tile landed) + lgkm (reads done)
  }
#undef STAGE

  // ---- epilogue, stage 1: acc -> LDS tile [128 t][128 h] bf16 (+bias) ----
#pragma unroll
  for (int fn = 0; fn < 4; fn++) {
    const int col = wc * 64 + fn * 16 + lr;
    const float bv = bias[n0 + col];
#pragma unroll
    for (int fm = 0; fm < 4; fm++) {
      const int row0 = wr * 64 + fm * 16 + (lane >> 4) * 4;
#pragma unroll
      for (int i = 0; i < 4; i++)
        lds[(row0 + i) * BN + col] = f2bf(acc[fm][fn][i] + bv);
    }
  }
  __syncthreads();

  // ---- epilogue, stage 2a: coalesced Yb store (256B rows) ----
  const int erow = tid >> 4;            // 0..15
  const int ecol = (tid & 15) * 8;      // elem offset, 16B per lane
#pragma unroll
  for (int p = 0; p < 8; p++) {
    const int row = p * 16 + erow;
    u16x8 v = *(const u16x8*)&lds[row * BN + ecol];
    *(u16x8*)&Yb[(size_t)(m0 + row) * N_H + n0 + ecol] = v;
  }

  // ---- epilogue, stage 2b: fused chunk-state over the LDS tile ----
  {
    const int bidx = m0 >> 12;           // m0 / T_SEQ
    const int c0   = (m0 & (T_SEQ - 1)) >> 5;  // first chunk in tile
    const int hl   = tid & 127;          // local h (same for both tasks)
    const int ck0  = tid >> 7;           // 0..1; tasks: ck0 and ck0+2
    const int h    = n0 + hl;

    float a[4], bb[4], cc[4], dd[4];
#pragma unroll
    for (int l = 0; l < 4; l++) {
      a[l]  = 1.f / (1.f + __expf(-As[l * N_H + h]));
      bb[l] = Bs[l * N_H + h];
      cc[l] = Cs[l * N_H + h];
      dd[l] = Ds[l * N_H + h];
    }

#pragma unroll
    for (int p = 0; p < 2; p++) {
      const int ck = ck0 + p * 2;
      float s[4] = {0.f, 0.f, 0.f, 0.f};
#pragma unroll 4
      for (int t = 0; t < LC; t++) {
        float xv = bf2f(lds[(ck * LC + t) * BN + hl]);
#pragma unroll
        for (int l = 0; l < 4; l++) {
          s[l] = fmaf(a[l], s[l], bb[l] * xv);
          xv = fmaf(cc[l], s[l], dd[l]);
        }
      }
      f32x4 e;
      e[0] = s[0]; e[1] = s[1]; e[2] = s[2]; e[3] = s[3];
      ((f32x4*)E)[(size_t)(bidx * NC + c0 + ck) * N_H + h] = e;
    }
  }
}

// ============ chunked parallel scan (passes B and C) ============
// Pass B: per-(b,h) serial combine over chunks with P=M^LC -> start states S.
__global__ __launch_bounds__(256) void chunk_scan_kernel(
    const float* __restrict__ A, const float* __restrict__ B,
    const float* __restrict__ C, const float* __restrict__ E,
    float* __restrict__ S) {
  const int idx = blockIdx.x * 256 + threadIdx.x;
  const int b = idx >> 10;
  const int h = idx & (N_H - 1);

  float a[4], bcoef[4], ccoef[4];
#pragma unroll
  for (int l = 0; l < 4; l++) {
    a[l] = 1.f / (1.f + __expf(-A[l * N_H + h]));
    bcoef[l] = B[l * N_H + h];
    ccoef[l] = C[l * N_H + h];
  }

  float m[4][4] = {};
  m[0][0] = a[0];
  m[1][0] = bcoef[1] * ccoef[0] * a[0];
  m[1][1] = a[1];
  m[2][0] = bcoef[2] * ccoef[1] * m[1][0];
  m[2][1] = bcoef[2] * ccoef[1] * a[1];
  m[2][2] = a[2];
  m[3][0] = bcoef[3] * ccoef[2] * m[2][0];
  m[3][1] = bcoef[3] * ccoef[2] * m[2][1];
  m[3][2] = bcoef[3] * ccoef[2] * a[2];
  m[3][3] = a[3];

  // P = M^LC, LC=32 -> 5 squarings
#pragma unroll
  for (int it = 0; it < 5; it++) {
    float t[4][4];
#pragma unroll
    for (int i = 0; i < 4; i++)
#pragma unroll
      for (int j = 0; j < 4; j++) {
        float acc = 0.f;
#pragma unroll
        for (int k = 0; k < 4; k++) acc = fmaf(m[i][k], m[k][j], acc);
        t[i][j] = acc;
      }
#pragma unroll
    for (int i = 0; i < 4; i++)
#pragma unroll
      for (int j = 0; j < 4; j++) m[i][j] = t[i][j];
  }

  float s[4] = {0.f, 0.f, 0.f, 0.f};
  const f32x4* Ep = (const f32x4*)E + (size_t)b * NC * N_H + h;
  f32x4* Sp = (f32x4*)S + (size_t)b * NC * N_H + h;
#pragma unroll 4
  for (int c = 0; c < NC; c++) {
    f32x4 sv;
    sv[0] = s[0]; sv[1] = s[1]; sv[2] = s[2]; sv[3] = s[3];
    Sp[(size_t)c * N_H] = sv;
    f32x4 e = Ep[(size_t)c * N_H];
    float ns[4];
#pragma unroll
    for (int i = 0; i < 4; i++) {
      float acc = e[i];
#pragma unroll
      for (int k = 0; k < 4; k++) acc = fmaf(m[i][k], s[k], acc);
      ns[i] = acc;
    }
#pragma unroll
    for (int i = 0; i < 4; i++) s[i] = ns[i];
  }
}

// Pass C: recurrence from exact start state; reads bf16 Y, writes f32 out.
// `out` is a 134 MB write-once stream -> NT stores (R12's measured -11us win).
// Reads stay cached (NT loads measured -15us, R14).
__global__ __launch_bounds__(256) void chunk_apply_kernel(
    const ushort* __restrict__ Yb, float* __restrict__ out,
    const float* __restrict__ A, const float* __restrict__ B,
    const float* __restrict__ C, const float* __restrict__ D,
    const float* __restrict__ S) {
  const int b  = blockIdx.x / NC;
  const int c  = blockIdx.x % NC;
  const int h4 = threadIdx.x << 2;

  float a[4][4], bb[4][4], cc[4][4], dd[4][4];
#pragma unroll
  for (int l = 0; l < 4; l++) {
    f32x4 av = *(const f32x4*)(A + l * N_H + h4);
    f32x4 bv = *(const f32x4*)(B + l * N_H + h4);
    f32x4 cv = *(const f32x4*)(C + l * N_H + h4);
    f32x4 dv = *(const f32x4*)(D + l * N_H + h4);
#pragma unroll
    for (int ch = 0; ch < 4; ch++) {
      a[l][ch]  = 1.f / (1.f + __expf(-av[ch]));
      bb[l][ch] = bv[ch]; cc[l][ch] = cv[ch]; dd[l][ch] = dv[ch];
    }
  }

  float s[4][4];
  const f32x4* sp = (const f32x4*)S + (size_t)(b * NC + c) * N_H + h4;
#pragma unroll
  for (int ch = 0; ch < 4; ch++) {
    f32x4 sv = sp[ch];
    s[0][ch] = sv[0]; s[1][ch] = sv[1]; s[2][ch] = sv[2]; s[3][ch] = sv[3];
  }

  const ushort* ybase = Yb + ((size_t)b * T_SEQ + (size_t)c * LC) * N_H + h4;
  f32x4* op = (f32x4*)(out + ((size_t)b * T_SEQ + (size_t)c * LC) * N_H) + (h4 >> 2);
#pragma unroll 4
  for (int t = 0; t < LC; t++) {
    u16x4 xv = *(const u16x4*)(ybase + (size_t)t * N_H);
    f32x4 ov;
#pragma unroll
    for (int ch = 0; ch < 4; ch++) {
      float x = bf2f(xv[ch]);
#pragma unroll
      for (int l = 0; l < 4; l++) {
        s[l][ch] = fmaf(a[l][ch], s[l][ch], bb[l][ch] * x);
        x = fmaf(cc[l][ch], s[l][ch], dd[l][ch]);
      }
      ov[ch] = x;
    }
    __builtin_nontemporal_store(ov, op + (size_t)t * (N_H / 4));
  }
}

extern "C" void kernel_launch(void* const* d_in, const int* in_sizes, int n_in,
                              void* d_out, int out_size, void* d_ws, size_t ws_size,
                              hipStream_t stream) {
  const float* x    = (const float*)d_in[0];
  const float* W    = (const float*)d_in[1];
  const float* b_in = (const float*)d_in[2];
  const float* A    = (const float*)d_in[3];
  const float* B    = (const float*)d_in[4];
  const float* C    = (const float*)d_in[5];
  const float* bias = (const float*)d_in[6];
  float* out = (float*)d_out;

  // ws layout (512 MiB available):
  //   xb  [0,   32 MiB)  bf16 x
  //   Wt  [32,  33 MiB)  bf16 W^T
  //   Yb  [40, 104 MiB)  bf16 intermediate Y
  //   E   [112,128 MiB)  f32 chunk end states
  //   S   [128,144 MiB)  f32 chunk start states
  char* wsb = (char*)d_ws;
  ushort* xb = (ushort*)wsb;
  ushort* Wt = (ushort*)(wsb + (size_t)33 * 1024 * 1024 - (size_t)N_H * K_F * 2);
  ushort* Yb = (ushort*)(wsb + (size_t)40 * 1024 * 1024);
  float*  E  = (float*)(wsb + (size_t)112 * 1024 * 1024);
  float*  S  = E + (size_t)BT * NC * N_H * 4;

  prep_kernel<<<CVT_BLOCKS + 512, 256, 0, stream>>>(x, xb, W, Wt);
  gemm_kernel<<<dim3(M_TOT / BM, N_H / BN), 256, 0, stream>>>(xb, Wt, b_in, Yb,
                                                              A, B, C, bias, E);
  chunk_scan_kernel<<<(BT * N_H) / 256, 256, 0, stream>>>(A, B, C, E, S);
  chunk_apply_kernel<<<BT * NC, 256, 0, stream>>>(Yb, out, A, B, C, bias, S);
}